// Round 4
// baseline (182.560 us; speedup 1.0000x reference)
//
#include <hip/hip_runtime.h>
#include <math.h>

// B=4, T=512, IDIM=128, HDIM=1024, CDIM=256
#define NROWS 2048
#define NBLK  1024            // 2 rows per block (one wave of 64)
#define NITER 4
#define IGNORE_OUT 10000.0f

__device__ __forceinline__ float readlanef(float v, int lane){
  return __int_as_float(__builtin_amdgcn_readlane(__float_as_int(v), lane));
}
// lane l receives lane (l-1)&63  (wavefront rotate right by 1)
__device__ __forceinline__ float rotup1(float v){
  int i = __float_as_int(v);
  return __int_as_float(__builtin_amdgcn_update_dpp(i, i, 0x13C, 0xF, 0xF, false));
}
// gather from a 128-vector held as two regs (v0: idx 0..63 at lane idx, v1: 64..127);
// returns 0 outside [0,128)
__device__ __forceinline__ float gather128(float v0, float v1, int idx){
  float g0 = __shfl(v0, idx & 63, 64);
  float g1 = __shfl(v1, idx & 63, 64);
  float r  = (idx & 64) ? g1 : g0;
  return ((unsigned)idx < 128u) ? r : 0.f;
}

// ---------- prep kernel ----------
// blocks 0..511 : Mt2T[i][d][o] = M_i[o][d] = sum_c w1[c,d]*w2[o,c]  (i=blk>>7, o=blk&127)
// blocks 512..515 : biasT[i][o] = b2[o] + sum_c b1[c]*w2[o,c]
// block 516 : zero the ticket
__global__ __launch_bounds__(256)
void prepK(const float* __restrict__ w1, const float* __restrict__ b1,
           const float* __restrict__ w2, const float* __restrict__ b2,
           float* __restrict__ Mt2T, float* __restrict__ biasT, int* __restrict__ ticket){
  __shared__ float part[256];
  const int blk = blockIdx.x;
  const int u = threadIdx.x;
  if (blk < 512){
    int i = blk >> 7, o = blk & 127;
    int d = u & 127, ch = u >> 7;
    const float* w1p = w1 + (i * 256 + ch * 128) * 128 + d;   // coalesced over d
    const float* w2p = w2 + o * 1024 + i * 256 + ch * 128;    // thread-uniform
    float a = 0.f;
    #pragma unroll 16
    for (int c = 0; c < 128; ++c) a = fmaf(w1p[c * 128], w2p[c], a);
    part[u] = a;
    __syncthreads();
    if (u < 128) Mt2T[(i * 128 + u) * 128 + o] = part[u] + part[u + 128]; // u = d
  } else if (blk < 516){
    int i = blk - 512;
    if (u < 128){
      const float* w2p = w2 + u * 1024 + i * 256;
      const float* b1p = b1 + i * 256;
      float a = b2[u];
      #pragma unroll 8
      for (int c = 0; c < 256; ++c) a = fmaf(b1p[c], w2p[c], a);
      biasT[i * 128 + u] = a;
    }
  } else {
    if (u == 0) *ticket = 0;
  }
}

// ---------- main kernel: one wave, TWO rows, zero LDS, zero barriers ----------
__global__ __launch_bounds__(64)
void mainK(const float* __restrict__ x, const float* __restrict__ y,
           const float* __restrict__ Mt2T, const float* __restrict__ biasT,
           unsigned long long* __restrict__ partials, int* __restrict__ ticket,
           float* __restrict__ out){
  const int l = threadIdx.x;               // 0..63
  const bool isl0 = (l == 0);
  const long b0 = (long)blockIdx.x * 256;

  // row0 = 2*bid, row1 = 2*bid+1 ; lo = elements 0..63, hi = 64..127
  float x0lo = x[b0 + l],        x0hi = x[b0 + 64 + l];
  float x1lo = x[b0 + 128 + l],  x1hi = x[b0 + 192 + l];
  float y0lo = y[b0 + l],        y0hi = y[b0 + 64 + l];
  float y1lo = y[b0 + 128 + l],  y1hi = y[b0 + 192 + l];
  const bool m0lo = (y0lo == IGNORE_OUT), m0hi = (y0hi == IGNORE_OUT);
  const bool m1lo = (y1lo == IGNORE_OUT), m1hi = (y1hi == IGNORE_OUT);
  float cnt = (m0lo?0.f:1.f) + (m0hi?0.f:1.f) + (m1lo?0.f:1.f) + (m1hi?0.f:1.f);
  float lossAcc = 0.f;

  for (int i = 0; i < NITER; ++i){
    // ---- prefix scan of x^2 (window norms), per row, registers only ----
    float p0a = x0lo * x0lo, p0b = x0hi * x0hi;
    float p1a = x1lo * x1lo, p1b = x1hi * x1hi;
    #pragma unroll
    for (int o2 = 1; o2 < 64; o2 <<= 1){
      float t0a = __shfl_up(p0a, o2, 64), t0b = __shfl_up(p0b, o2, 64);
      float t1a = __shfl_up(p1a, o2, 64), t1b = __shfl_up(p1b, o2, 64);
      if (l >= o2){ p0a += t0a; p0b += t0b; p1a += t1a; p1b += t1b; }
    }
    float tot0_0 = readlanef(p0a, 63), tot0_1 = readlanef(p1a, 63);
    float prefA0 = p0a, prefB0 = p0b + tot0_0;
    float prefA1 = p1a, prefB1 = p1b + tot0_1;
    float total0 = readlanef(p0b, 63) + tot0_0;
    float total1 = readlanef(p1b, 63) + tot0_1;

    // ---- ||y_res||^2 per row ----
    float ny0 = y0lo * y0lo + y0hi * y0hi;
    float ny1 = y1lo * y1lo + y1hi * y1hi;
    #pragma unroll
    for (int o2 = 32; o2; o2 >>= 1){
      ny0 += __shfl_xor(ny0, o2, 64);
      ny1 += __shfl_xor(ny1, o2, 64);
    }

    // ---- register-rotation Toeplitz correlation ----
    // a(j)(l) = y[(127-l+j)%128], b(j)(l) = y[(63-l+j)%128]; product with uniform x[j].
    // ntX = full sum (shift t and t+128 combined); n1X = snapshot at j==t (sum j<=t).
    float a0 = __shfl(y0hi, 63 - l, 64), b0r = __shfl(y0lo, 63 - l, 64);
    float a1 = __shfl(y1hi, 63 - l, 64), b1r = __shfl(y1lo, 63 - l, 64);
    float ntA0 = 0.f, n1A0 = 0.f, ntB0 = 0.f, n1B0 = 0.f;
    float ntA1 = 0.f, n1A1 = 0.f, ntB1 = 0.f, n1B1 = 0.f;
    #pragma unroll 4
    for (int j = 0; j < 64; ++j){
      float sx0 = readlanef(x0lo, j);
      float sx1 = readlanef(x1lo, j);
      ntA0 = fmaf(a0, sx0, ntA0);  ntB0 = fmaf(b0r, sx0, ntB0);
      ntA1 = fmaf(a1, sx1, ntA1);  ntB1 = fmaf(b1r, sx1, ntB1);
      bool snap = (j == l);                       // pair-A boundary (t = l)
      n1A0 = snap ? ntA0 : n1A0;
      n1A1 = snap ? ntA1 : n1A1;
      float r0 = rotup1(a0), r1 = rotup1(b0r);
      a0  = isl0 ? r1 : r0;  b0r = isl0 ? r0 : r1;
      float r2 = rotup1(a1), r3 = rotup1(b1r);
      a1  = isl0 ? r3 : r2;  b1r = isl0 ? r2 : r3;
    }
    #pragma unroll 4
    for (int j = 64; j < 128; ++j){
      float sx0 = readlanef(x0hi, j - 64);
      float sx1 = readlanef(x1hi, j - 64);
      ntA0 = fmaf(a0, sx0, ntA0);  ntB0 = fmaf(b0r, sx0, ntB0);
      ntA1 = fmaf(a1, sx1, ntA1);  ntB1 = fmaf(b1r, sx1, ntB1);
      bool snap = ((j - 64) == l);                // pair-B boundary (t = l+64)
      n1B0 = snap ? ntB0 : n1B0;
      n1B1 = snap ? ntB1 : n1B1;
      float r0 = rotup1(a0), r1 = rotup1(b0r);
      a0  = isl0 ? r1 : r0;  b0r = isl0 ? r0 : r1;
      float r2 = rotup1(a1), r3 = rotup1(b1r);
      a1  = isl0 ? r3 : r2;  b1r = isl0 ? r2 : r3;
    }

    // ---- cosine sims + first-max argmax (per row): shifts {l, l+64, l+128, l+192} ----
    int sstar0, sstar1;
    {
      float nY = sqrtf(ny0);
      float dA1 = nY * sqrtf(prefA0),                    dB1 = nY * sqrtf(prefB0);
      float dA2 = nY * sqrtf(fmaxf(total0 - prefA0, 0.f)), dB2 = nY * sqrtf(fmaxf(total0 - prefB0, 0.f));
      float sA1 = (dA1 == 0.f) ? 0.f : n1A0 / dA1;
      float sB1 = (dB1 == 0.f) ? 0.f : n1B0 / dB1;
      float sA2 = (dA2 == 0.f) ? 0.f : (ntA0 - n1A0) / dA2;
      float sB2 = (dB2 == 0.f) ? 0.f : (ntB0 - n1B0) / dB2;
      if (l == 63) sB2 = -INFINITY;
      float bv = sA1; int bi = l;
      if (sB1 > bv){ bv = sB1; bi = l + 64;  }
      if (sA2 > bv){ bv = sA2; bi = l + 128; }
      if (sB2 > bv){ bv = sB2; bi = l + 192; }
      #pragma unroll
      for (int o2 = 1; o2 < 64; o2 <<= 1){
        float ov = __shfl_xor(bv, o2, 64);
        int   oi = __shfl_xor(bi, o2, 64);
        if (ov > bv || (ov == bv && oi < bi)){ bv = ov; bi = oi; }
      }
      sstar0 = bi;
    }
    {
      float nY = sqrtf(ny1);
      float dA1 = nY * sqrtf(prefA1),                    dB1 = nY * sqrtf(prefB1);
      float dA2 = nY * sqrtf(fmaxf(total1 - prefA1, 0.f)), dB2 = nY * sqrtf(fmaxf(total1 - prefB1, 0.f));
      float sA1 = (dA1 == 0.f) ? 0.f : n1A1 / dA1;
      float sB1 = (dB1 == 0.f) ? 0.f : n1B1 / dB1;
      float sA2 = (dA2 == 0.f) ? 0.f : (ntA1 - n1A1) / dA2;
      float sB2 = (dB2 == 0.f) ? 0.f : (ntB1 - n1B1) / dB2;
      if (l == 63) sB2 = -INFINITY;
      float bv = sA1; int bi = l;
      if (sB1 > bv){ bv = sB1; bi = l + 64;  }
      if (sA2 > bv){ bv = sA2; bi = l + 128; }
      if (sB2 > bv){ bv = sB2; bi = l + 192; }
      #pragma unroll
      for (int o2 = 1; o2 < 64; o2 <<= 1){
        float ov = __shfl_xor(bv, o2, 64);
        int   oi = __shfl_xor(bi, o2, 64);
        if (ov > bv || (ov == bv && oi < bi)){ bv = ov; bi = oi; }
      }
      sstar1 = bi;
    }

    // ---- x_aug + detached softmax + reverse-shift x_res update (per row) ----
    float w0lo, w0hi, w1lo, w1hi;
    {
      int j0 = sstar0 + l - 127;
      float xa = gather128(x0lo, x0hi, j0);
      float xb = gather128(x0lo, x0hi, j0 + 64);
      float za = xa * y0lo, zb = xb * y0hi;
      float mz = fmaxf(za, zb);
      #pragma unroll
      for (int o2 = 32; o2; o2 >>= 1) mz = fmaxf(mz, __shfl_xor(mz, o2, 64));
      float ea = expf(za - mz), eb = expf(zb - mz);
      float se = ea + eb;
      #pragma unroll
      for (int o2 = 32; o2; o2 >>= 1) se += __shfl_xor(se, o2, 64);
      w0lo = xa * (ea / se); w0hi = xb * (eb / se);
      int k0 = l + 127 - sstar0;
      x0lo -= gather128(w0lo, w0hi, k0);
      x0hi -= gather128(w0lo, w0hi, k0 + 64);
    }
    {
      int j0 = sstar1 + l - 127;
      float xa = gather128(x1lo, x1hi, j0);
      float xb = gather128(x1lo, x1hi, j0 + 64);
      float za = xa * y1lo, zb = xb * y1hi;
      float mz = fmaxf(za, zb);
      #pragma unroll
      for (int o2 = 32; o2; o2 >>= 1) mz = fmaxf(mz, __shfl_xor(mz, o2, 64));
      float ea = expf(za - mz), eb = expf(zb - mz);
      float se = ea + eb;
      #pragma unroll
      for (int o2 = 32; o2; o2 >>= 1) se += __shfl_xor(se, o2, 64);
      w1lo = xa * (ea / se); w1hi = xb * (eb / se);
      int k0 = l + 127 - sstar1;
      x1lo -= gather128(w1lo, w1hi, k0);
      x1hi -= gather128(w1lo, w1hi, k0 + 64);
    }

    // ---- MLP: y_ele[o] = sum_d Mt2T[i][d][o] * xatt[d]; M/bias shared across rows ----
    const float* Mi = Mt2T + i * 16384;
    float aA0 = 0.f, aB0 = 0.f, aA1 = 0.f, aB1 = 0.f;
    #pragma unroll 4
    for (int d = 0; d < 64; ++d){
      float mlo = Mi[d * 128 + l];          // coalesced b32
      float mhi = Mi[d * 128 + 64 + l];
      float s0 = readlanef(w0lo, d);
      float s1 = readlanef(w1lo, d);
      aA0 = fmaf(mlo, s0, aA0); aB0 = fmaf(mhi, s0, aB0);
      aA1 = fmaf(mlo, s1, aA1); aB1 = fmaf(mhi, s1, aB1);
    }
    #pragma unroll 4
    for (int d = 64; d < 128; ++d){
      float mlo = Mi[d * 128 + l];
      float mhi = Mi[d * 128 + 64 + l];
      float s0 = readlanef(w0hi, d - 64);
      float s1 = readlanef(w1hi, d - 64);
      aA0 = fmaf(mlo, s0, aA0); aB0 = fmaf(mhi, s0, aB0);
      aA1 = fmaf(mlo, s1, aA1); aB1 = fmaf(mhi, s1, aB1);
    }
    float blo = biasT[i * 128 + l], bhi = biasT[i * 128 + 64 + l];

    // ---- loss + y_res update ----
    {
      float dlo = (aA0 + blo) - y0lo, dhi = (aB0 + bhi) - y0hi;
      if (!m0lo) lossAcc = fmaf(dlo, dlo, lossAcc);
      if (!m0hi) lossAcc = fmaf(dhi, dhi, lossAcc);
      y0lo = -dlo; y0hi = -dhi;
    }
    {
      float dlo = (aA1 + blo) - y1lo, dhi = (aB1 + bhi) - y1hi;
      if (!m1lo) lossAcc = fmaf(dlo, dlo, lossAcc);
      if (!m1hi) lossAcc = fmaf(dhi, dhi, lossAcc);
      y1lo = -dlo; y1hi = -dhi;
    }
  }

  // ---- block partial + ticket; last block reduces and writes out ----
  #pragma unroll
  for (int o2 = 32; o2; o2 >>= 1){
    lossAcc += __shfl_xor(lossAcc, o2, 64);
    cnt     += __shfl_xor(cnt,     o2, 64);
  }
  int old = 0;
  if (l == 0){
    union { float2 f; unsigned long long u; } pk;
    pk.f.x = lossAcc; pk.f.y = cnt;
    __hip_atomic_store(&partials[blockIdx.x], pk.u, __ATOMIC_RELEASE, __HIP_MEMORY_SCOPE_AGENT);
    old = __hip_atomic_fetch_add(ticket, 1, __ATOMIC_ACQ_REL, __HIP_MEMORY_SCOPE_AGENT);
  }
  old = __shfl(old, 0, 64);
  if (old == NBLK - 1){
    float ls = 0.f, cs = 0.f;
    for (int g = l; g < NBLK; g += 64){
      union { float2 f; unsigned long long u; } pk;
      pk.u = __hip_atomic_load(&partials[g], __ATOMIC_ACQUIRE, __HIP_MEMORY_SCOPE_AGENT);
      ls += pk.f.x; cs += pk.f.y;
    }
    #pragma unroll
    for (int o2 = 32; o2; o2 >>= 1){
      ls += __shfl_xor(ls, o2, 64);
      cs += __shfl_xor(cs, o2, 64);
    }
    if (l == 0) out[0] = ls / ((float)NITER * cs);
  }
}

extern "C" void kernel_launch(void* const* d_in, const int* in_sizes, int n_in,
                              void* d_out, int out_size, void* d_ws, size_t ws_size,
                              hipStream_t stream){
  const float* x  = (const float*)d_in[0];
  const float* y  = (const float*)d_in[1];
  const float* w1 = (const float*)d_in[2];
  const float* b1 = (const float*)d_in[3];
  const float* w2 = (const float*)d_in[4];
  const float* b2 = (const float*)d_in[5];
  float* out = (float*)d_out;

  // ws layout: [0,4) ticket ; [256, 256+256K) Mt2T ; +2K biasT ; +8K partials
  int*   ticket = (int*)d_ws;
  float* Mt2T   = (float*)((char*)d_ws + 256);
  float* biasT  = (float*)((char*)d_ws + 256 + 4 * 128 * 128 * sizeof(float));
  unsigned long long* partials =
      (unsigned long long*)((char*)d_ws + 256 + 4 * 128 * 128 * sizeof(float) + 4 * 128 * sizeof(float));

  prepK<<<517, 256, 0, stream>>>(w1, b1, w2, b2, Mt2T, biasT, ticket);
  mainK<<<NBLK, 64, 0, stream>>>(x, y, Mt2T, biasT, partials, ticket, out);
}

// Round 5
// 166.145 us; speedup vs baseline: 1.0988x; 1.0988x over previous
//
#include <hip/hip_runtime.h>
#include <math.h>

// B=4, T=512, IDIM=128, HDIM=1024, CDIM=256
#define NROWS 2048
#define NBLK  2048            // one row per block, 2 waves per block
#define NITER 4
#define IGNORE_OUT 10000.0f

__device__ __forceinline__ float readlanef(float v, int lane){
  return __int_as_float(__builtin_amdgcn_readlane(__float_as_int(v), lane));
}
// lane l receives lane (l-1)&63  (wavefront rotate right by 1)
__device__ __forceinline__ float rotup1(float v){
  int i = __float_as_int(v);
  return __int_as_float(__builtin_amdgcn_update_dpp(i, i, 0x13C, 0xF, 0xF, false));
}
// gather from 128-vector held as two regs; 0 outside [0,128)
__device__ __forceinline__ float gather128(float v0, float v1, int idx){
  float g0 = __shfl(v0, idx & 63, 64);
  float g1 = __shfl(v1, idx & 63, 64);
  float r  = (idx & 64) ? g1 : g0;
  return ((unsigned)idx < 128u) ? r : 0.f;
}
__device__ __forceinline__ float bflySum(float v){
  #pragma unroll
  for (int o = 32; o; o >>= 1) v += __shfl_xor(v, o, 64);
  return v;
}
__device__ __forceinline__ float bflyMax(float v){
  #pragma unroll
  for (int o = 32; o; o >>= 1) v = fmaxf(v, __shfl_xor(v, o, 64));
  return v;
}

// ---------- prep kernel ----------
// blocks 0..511 : G[d][o] = sum_c w1[c,d]*w2[o,c] stored quad-packed:
//   M4[i][dd][o] = float4(G[4dd][o],G[4dd+1][o],G[4dd+2][o],G[4dd+3][o])
//   float index: i*16384 + dd*512 + o*4 + e
// blocks 512..515 : biasT[i][o] = b2[o] + sum_c b1[c]*w2[o,c]
// block 516 : zero the ticket
__global__ __launch_bounds__(128)
void prepK(const float* __restrict__ w1, const float* __restrict__ b1,
           const float* __restrict__ w2, const float* __restrict__ b2,
           float* __restrict__ M4, float* __restrict__ biasT, int* __restrict__ ticket){
  const int blk = blockIdx.x;
  const int u = threadIdx.x;
  if (blk < 512){
    int i = blk >> 7, o = blk & 127;
    const float* w1p = w1 + (i * 256) * 128 + u;   // coalesced over d=u
    const float* w2p = w2 + o * 1024 + i * 256;    // thread-uniform
    float a = 0.f;
    #pragma unroll 16
    for (int c = 0; c < 256; ++c) a = fmaf(w1p[c * 128], w2p[c], a);
    M4[i * 16384 + (u >> 2) * 512 + o * 4 + (u & 3)] = a;
  } else if (blk < 516){
    int i = blk - 512;
    const float* w2p = w2 + u * 1024 + i * 256;
    const float* b1p = b1 + i * 256;
    float a = b2[u];
    #pragma unroll 8
    for (int c = 0; c < 256; ++c) a = fmaf(b1p[c], w2p[c], a);
    biasT[i * 128 + u] = a;
  } else {
    if (u == 0) *ticket = 0;
  }
}

// ---------- main kernel: one row per block, 2 waves split corr windows + MLP halves ----------
__global__ __launch_bounds__(128, 4)
void mainK(const float* __restrict__ x, const float* __restrict__ y,
           const float* __restrict__ M4, const float* __restrict__ biasT,
           unsigned long long* __restrict__ partials, int* __restrict__ ticket,
           float* __restrict__ out){
  __shared__ float sVal[2];
  __shared__ int   sIdx[2];
  __shared__ float yel[128];
  __shared__ float sL[2], sC[2];
  __shared__ int   sOld;

  const int u = threadIdx.x;               // 0..127 (= output index o in MLP)
  const int l = u & 63;
  const int w = u >> 6;                    // wave id 0/1
  const bool isl0 = (l == 0);
  const long base = (long)blockIdx.x * 128;

  // both waves hold the FULL row in registers
  float xlo = x[base + l],      xhi = x[base + 64 + l];
  float ylo = y[base + l],      yhi = y[base + 64 + l];
  const bool mlo = (ylo == IGNORE_OUT), mhi = (yhi == IGNORE_OUT);
  const bool ownM = w ? mhi : mlo;         // wave owns its half for loss/cnt
  float cnt = ownM ? 0.f : 1.f;
  float lossAcc = 0.f;

  for (int i = 0; i < NITER; ++i){
    // ---- window norms: each wave scans ITS half, butterfly-sums the other ----
    float sq_lo = xlo * xlo, sq_hi = xhi * xhi;
    float v = w ? sq_hi : sq_lo;
    #pragma unroll
    for (int o2 = 1; o2 < 64; o2 <<= 1){
      float tv = __shfl_up(v, o2, 64);
      if (l >= o2) v += tv;
    }
    float osum  = bflySum(w ? sq_lo : sq_hi);
    float total = readlanef(v, 63) + osum;
    float pref_t = w ? (v + osum) : v;     // inclusive prefix at t = 64w + l

    // ---- ||y_res||^2 ----
    float nY = sqrtf(bflySum(ylo * ylo + yhi * yhi));

    // ---- corr: wave w rotates its window; ring-coupling value from registers ----
    // wave0 window a(j)[l] = y[(127-l+j)%128]  (pair t=l)
    // wave1 window b(j)[l] = y[(63-l+j)%128]   (pair t=l+64)
    float nt = 0.f, n1 = 0.f;
    {
      float src0 = w ? ylo : yhi;
      float win = __shfl(src0, 63 - l, 64);
      if (w == 0){
        #pragma unroll 8
        for (int j = 0; j < 64; ++j){      // snaps only here (t=l in [0,63])
          float sx = readlanef(xlo, j);
          nt = fmaf(win, sx, nt);
          n1 = (j == l) ? nt : n1;
          float inc = readlanef(ylo, j);   // incoming lane0 value = y[j]
          float r = rotup1(win);
          win = isl0 ? inc : r;
        }
        #pragma unroll 8
        for (int j = 0; j < 64; ++j){
          float sx = readlanef(xhi, j);
          nt = fmaf(win, sx, nt);
          float inc = readlanef(yhi, j);   // y[64+j]... = y[j+64] -> incoming y[(j+64)]%128 = yhi[j]
          float r = rotup1(win);
          win = isl0 ? inc : r;
        }
      } else {
        #pragma unroll 8
        for (int j = 0; j < 64; ++j){
          float sx = readlanef(xlo, j);
          nt = fmaf(win, sx, nt);
          float inc = readlanef(yhi, j);   // incoming = y[64+j]
          float r = rotup1(win);
          win = isl0 ? inc : r;
        }
        #pragma unroll 8
        for (int j = 0; j < 64; ++j){      // snaps here (t-64 = l)
          float sx = readlanef(xhi, j);
          nt = fmaf(win, sx, nt);
          n1 = (j == l) ? nt : n1;
          float inc = readlanef(ylo, j);   // incoming = y[j] (wrapped)
          float r = rotup1(win);
          win = isl0 ? inc : r;
        }
      }
    }

    // ---- cosine sims for shifts t=64w+l and t+128; wave argmax; cross-wave combine ----
    {
      float num1 = n1, num2 = nt - n1;
      float d1 = nY * sqrtf(pref_t);
      float d2 = nY * sqrtf(fmaxf(total - pref_t, 0.f));
      float s1 = (d1 == 0.f) ? 0.f : num1 / d1;
      float s2 = (d2 == 0.f) ? 0.f : num2 / d2;
      int tsh = (w << 6) | l;
      if (tsh == 127) s2 = -INFINITY;      // shift 255 doesn't exist
      float bv = s1; int bi = tsh;
      if (s2 > bv){ bv = s2; bi = tsh + 128; }
      #pragma unroll
      for (int o2 = 1; o2 < 64; o2 <<= 1){
        float ov = __shfl_xor(bv, o2, 64);
        int   oi = __shfl_xor(bi, o2, 64);
        if (ov > bv || (ov == bv && oi < bi)){ bv = ov; bi = oi; }
      }
      if (l == 0){ sVal[w] = bv; sIdx[w] = bi; }
    }
    __syncthreads();
    int sstar;
    {
      float v0 = sVal[0], v1 = sVal[1];
      int   i0 = sIdx[0], i1 = sIdx[1];
      sstar = (v1 > v0 || (v1 == v0 && i1 < i0)) ? i1 : i0;
    }

    // ---- x_aug + detached softmax (duplicated per wave, registers only) ----
    int j0 = sstar + l - 127;
    float xa = gather128(xlo, xhi, j0);
    float xb = gather128(xlo, xhi, j0 + 64);
    float za = xa * ylo, zb = xb * yhi;
    float mz = bflyMax(fmaxf(za, zb));
    float ea = expf(za - mz), eb = expf(zb - mz);
    float se = bflySum(ea + eb);
    float wlo = xa * (ea / se), whi = xb * (eb / se);   // xatt (identical in both waves)

    // ---- x_res update (reverse shift) ----
    int k0 = l + 127 - sstar;
    xlo -= gather128(wlo, whi, k0);
    xhi -= gather128(wlo, whi, k0 + 64);

    // ---- MLP: wave w computes output o = u; 32 coalesced b128 loads ----
    float ye;
    {
      const float4* Mp = (const float4*)(M4 + (size_t)i * 16384);
      float av = 0.f;
      #pragma unroll
      for (int dd = 0; dd < 16; ++dd){
        float4 m = Mp[dd * 128 + u];
        av = fmaf(m.x, readlanef(wlo, 4 * dd + 0), av);
        av = fmaf(m.y, readlanef(wlo, 4 * dd + 1), av);
        av = fmaf(m.z, readlanef(wlo, 4 * dd + 2), av);
        av = fmaf(m.w, readlanef(wlo, 4 * dd + 3), av);
      }
      #pragma unroll
      for (int dd = 16; dd < 32; ++dd){
        float4 m = Mp[dd * 128 + u];
        int b = 4 * dd - 64;
        av = fmaf(m.x, readlanef(whi, b + 0), av);
        av = fmaf(m.y, readlanef(whi, b + 1), av);
        av = fmaf(m.z, readlanef(whi, b + 2), av);
        av = fmaf(m.w, readlanef(whi, b + 3), av);
      }
      ye = av + biasT[i * 128 + u];
    }
    // own-half loss before exchange (each element counted exactly once)
    {
      float yown = w ? yhi : ylo;
      float dOwn = ye - yown;
      if (!ownM) lossAcc = fmaf(dOwn, dOwn, lossAcc);
    }
    yel[u] = ye;
    __syncthreads();
    {
      float dlo = yel[l] - ylo, dhi = yel[64 + l] - yhi;
      ylo = -dlo; yhi = -dhi;              // y_res -= y_ele
    }
  }

  // ---- block loss/cnt, partial store + ticket; last block finalizes ----
  lossAcc = bflySum(lossAcc);
  cnt     = bflySum(cnt);
  if (l == 0){ sL[w] = lossAcc; sC[w] = cnt; }
  __syncthreads();
  if (u == 0){
    union { float2 f; unsigned long long v; } pk;
    pk.f.x = sL[0] + sL[1]; pk.f.y = sC[0] + sC[1];
    __hip_atomic_store(&partials[blockIdx.x], pk.v, __ATOMIC_RELEASE, __HIP_MEMORY_SCOPE_AGENT);
    sOld = __hip_atomic_fetch_add(ticket, 1, __ATOMIC_ACQ_REL, __HIP_MEMORY_SCOPE_AGENT);
  }
  __syncthreads();
  if (sOld == NBLK - 1){
    float ls = 0.f, cs = 0.f;
    for (int g = u; g < NBLK; g += 128){
      union { float2 f; unsigned long long v; } pk;
      pk.v = __hip_atomic_load(&partials[g], __ATOMIC_ACQUIRE, __HIP_MEMORY_SCOPE_AGENT);
      ls += pk.f.x; cs += pk.f.y;
    }
    ls = bflySum(ls); cs = bflySum(cs);
    if (l == 0){ sL[w] = ls; sC[w] = cs; }
    __syncthreads();
    if (u == 0) out[0] = (sL[0] + sL[1]) / ((float)NITER * (sC[0] + sC[1]));
  }
}

extern "C" void kernel_launch(void* const* d_in, const int* in_sizes, int n_in,
                              void* d_out, int out_size, void* d_ws, size_t ws_size,
                              hipStream_t stream){
  const float* x  = (const float*)d_in[0];
  const float* y  = (const float*)d_in[1];
  const float* w1 = (const float*)d_in[2];
  const float* b1 = (const float*)d_in[3];
  const float* w2 = (const float*)d_in[4];
  const float* b2 = (const float*)d_in[5];
  float* out = (float*)d_out;

  // ws: [0,4) ticket ; [256, 256+256K) M4 ; +2K biasT ; +16K partials
  int*   ticket = (int*)d_ws;
  float* M4     = (float*)((char*)d_ws + 256);
  float* biasT  = (float*)((char*)d_ws + 256 + 4 * 128 * 128 * sizeof(float));
  unsigned long long* partials =
      (unsigned long long*)((char*)d_ws + 256 + 4 * 128 * 128 * sizeof(float) + 4 * 128 * sizeof(float));

  prepK<<<517, 128, 0, stream>>>(w1, b1, w2, b2, M4, biasT, ticket);
  mainK<<<NBLK, 128, 0, stream>>>(x, y, M4, biasT, partials, ticket, out);
}